// Round 6
// baseline (7113.847 us; speedup 1.0000x reference)
//
#include <hip/hip_runtime.h>

// Problem dims (fixed by reference)
#define T_SEQ 512
#define B_SZ  64
#define IN_SZ 512
#define H_SZ  1024
#define NBLK  256   // 128 blocks layer0 + 128 blocks layer1, 1 block/CU (LDS-forced)
#define NTHR  512   // 8 waves = 4 m-tiles x 2 k-halves

typedef _Float16 f16;
typedef _Float16 half8 __attribute__((ext_vector_type(8)));
typedef float    f32x4 __attribute__((ext_vector_type(4)));

// LDS layout (dynamic): wfrag [0,128K) | P tiles 8x1KB | c 2KB | bias 128B
#define SM_WFRAG 0
#define SM_PART  131072
#define SM_C     (131072 + 8192)
#define SM_BIAS  (131072 + 8192 + 2048)
#define SMEM_BYTES (131072 + 8192 + 2048 + 128)

struct Params {
    const float *x;
    const float *wih0, *whh0, *bih0, *bhh0;
    const float *wih1, *whh1, *bih1, *bhh1;
    f16 *h1all;    // [T][B][H]  rotating addresses: consumers use plain cached loads
    f16 *h2all;    // [T][B][H]
    int *flags0, *flags1;   // 128 ints each, PACKED (512B): poll = 1 long load/lane
};

__device__ __forceinline__ float sigf(float x)     { return 1.f / (1.f + __expf(-x)); }
__device__ __forceinline__ float tanhfast(float x) { return 2.f / (1.f + __expf(-2.f * x)) - 1.f; }

// ---------------------------------------------------------------------------
// Persistent 2-layer LSTM, fence-free coherence (R5) + packed-flag polling +
// tree-free wave partition: wave = (m-tile, k-half); each wave owns 2 final
// 16x16 output tiles (nt=0: gates i,f; nt=1: gates g,o) over half of K.
// One LDS exchange merges the two k-halves -> 2 barriers, no reduction tree.
// ---------------------------------------------------------------------------
__global__ __launch_bounds__(NTHR, 2) void persist_kernel(Params p)
{
    extern __shared__ char smem[];
    f16*   wfrag = (f16*)(smem + SM_WFRAG);
    float* P     = (float*)(smem + SM_PART);   // 8 slots x 256 f32, lane-dump layout
    float* c_lds = (float*)(smem + SM_C);      // [64][8] cell state, persistent
    float* bl    = (float*)(smem + SM_BIAS);   // [4 gates][8 cols]

    const int tid = threadIdx.x;
    const int l   = tid & 63, wv = tid >> 6;
    const int n16 = l & 15,  q  = l >> 4;
    const int mt  = wv & 3,  kp = wv >> 2;     // m-tile, k-half
    const int layer = blockIdx.x >> 7;
    const int bid   = blockIdx.x & 127;
    const int jb    = bid * 8;

    // ---- one-time staging: weights fp32 -> f16 fragments in LDS ----
    // frag f = kg*2 + nt; nt=0 holds gates {i,f}, nt=1 holds {g,o} for cols jb..jb+7
    {
        const int gate0 = n16 >> 3, c8 = n16 & 7;
        const int nfrag = layer ? 128 : 96;   // (K/32)*2
        for (int f = wv; f < nfrag; f += 8) {
            int kstep = f >> 1, nt = f & 1;
            int wrow = (nt * 2 + gate0) * H_SZ + jb + c8;
            const float* src;
            if (layer == 0) {
                src = (kstep < 16) ? p.wih0 + (size_t)wrow * IN_SZ + kstep * 32 + q * 8
                                   : p.whh0 + (size_t)wrow * H_SZ + (kstep - 16) * 32 + q * 8;
            } else {
                src = (kstep < 32) ? p.wih1 + (size_t)wrow * H_SZ + kstep * 32 + q * 8
                                   : p.whh1 + (size_t)wrow * H_SZ + (kstep - 32) * 32 + q * 8;
            }
            half8 hv;
            #pragma unroll
            for (int u = 0; u < 8; ++u) hv[u] = (f16)src[u];
            *(half8*)(wfrag + f * 512 + l * 8) = hv;
        }
        if (tid < 32) {
            int gate = tid >> 3, col = tid & 7;
            int wrow = gate * H_SZ + jb + col;
            bl[tid] = layer ? (p.bih1[wrow] + p.bhh1[wrow])
                            : (p.bih0[wrow] + p.bhh0[wrow]);
        }
        c_lds[tid] = 0.f;   // 512 = 64x8 exactly
    }
    __syncthreads();

    auto ldB = [&](int kg, int nt) -> half8 {
        return *(const half8*)(wfrag + (kg * 2 + nt) * 512 + l * 8);
    };
    // lane-dump tile layout: conflict-free contiguous b128 per wave
    auto wtile = [&](int slot, const f32x4& v) {
        *(f32x4*)(P + slot * 256 + l * 4) = v;
    };
    auto atile = [&](int slot, f32x4& a) {
        a += *(const f32x4*)(P + slot * 256 + l * 4);
    };
    int* myflag = (layer ? p.flags1 : p.flags0) + bid;

    for (int s = 0; s < T_SEQ; ++s) {
        f32x4 acc0 = {}, acc1 = {};   // nt=0 (i,f), nt=1 (g,o) for this wave's m-tile

        if (layer == 0) {
            // -- x part pre-poll (no cross-block dependency): kgs kp*8 .. +8
            #pragma unroll
            for (int u = 0; u < 8; ++u) {
                int kg = kp * 8 + u;
                int kb = kg * 32 + q * 8;
                half8 b0 = ldB(kg, 0), b1 = ldB(kg, 1);
                const float* ap = p.x + ((size_t)(mt * 16 + n16) * T_SEQ + s) * IN_SZ + kb;
                f32x4 xa = *(const f32x4*)ap;
                f32x4 xb = *(const f32x4*)(ap + 4);
                half8 af;
                #pragma unroll
                for (int u2 = 0; u2 < 4; ++u2) { af[u2] = (f16)xa[u2]; af[4 + u2] = (f16)xb[u2]; }
                acc0 = __builtin_amdgcn_mfma_f32_16x16x32_f16(af, b0, acc0, 0, 0, 0);
                acc1 = __builtin_amdgcn_mfma_f32_16x16x32_f16(af, b1, acc1, 0, 0, 0);
            }
            if (s > 0) {
                // ---- wait: own group finished s-1 (packed-flag poll, wave 0) ----
                if (wv == 0) {
                    const long* f0 = (const long*)p.flags0;
                    bool d = false;
                    while (true) {
                        if (!d) {
                            long v = __hip_atomic_load(f0 + l, __ATOMIC_RELAXED, __HIP_MEMORY_SCOPE_AGENT);
                            d = (int)v >= s && (int)(v >> 32) >= s;
                        }
                        if (__all(d)) break;
                        __builtin_amdgcn_s_sleep(2);
                    }
                }
                __syncthreads();
                // -- recurrent part: h1[s-1], kgs 16 + kp*16 .. +16
                const f16* hp = p.h1all + (size_t)(s - 1) * (B_SZ * H_SZ);
                #pragma unroll
                for (int u = 0; u < 16; ++u) {
                    int kg = 16 + kp * 16 + u;
                    int kb = (kg - 16) * 32 + q * 8;
                    half8 b0 = ldB(kg, 0), b1 = ldB(kg, 1);
                    half8 af = *(const half8*)(hp + (size_t)(mt * 16 + n16) * H_SZ + kb);
                    acc0 = __builtin_amdgcn_mfma_f32_16x16x32_f16(af, b0, acc0, 0, 0, 0);
                    acc1 = __builtin_amdgcn_mfma_f32_16x16x32_f16(af, b1, acc1, 0, 0, 0);
                }
            }
        } else {
            // ---- wait: h1[s] published (flags0>=s+1); own group done s-1 (flags1>=s)
            {
                if (wv == 0) {
                    const long* f0 = (const long*)p.flags0;
                    const long* f1 = (const long*)p.flags1;
                    int tA = s + 1, tB = s;
                    bool dA = false, dB = false;
                    while (true) {
                        if (!dA) {
                            long v = __hip_atomic_load(f0 + l, __ATOMIC_RELAXED, __HIP_MEMORY_SCOPE_AGENT);
                            dA = (int)v >= tA && (int)(v >> 32) >= tA;
                        }
                        if (!dB) {
                            long v = __hip_atomic_load(f1 + l, __ATOMIC_RELAXED, __HIP_MEMORY_SCOPE_AGENT);
                            dB = (int)v >= tB && (int)(v >> 32) >= tB;
                        }
                        if (__all(dA && dB)) break;
                        __builtin_amdgcn_s_sleep(2);
                    }
                }
                __syncthreads();
            }
            // -- input part: h1[s], kgs kp*16 .. +16
            {
                const f16* hp = p.h1all + (size_t)s * (B_SZ * H_SZ);
                #pragma unroll
                for (int u = 0; u < 16; ++u) {
                    int kg = kp * 16 + u;
                    int kb = kg * 32 + q * 8;
                    half8 b0 = ldB(kg, 0), b1 = ldB(kg, 1);
                    half8 af = *(const half8*)(hp + (size_t)(mt * 16 + n16) * H_SZ + kb);
                    acc0 = __builtin_amdgcn_mfma_f32_16x16x32_f16(af, b0, acc0, 0, 0, 0);
                    acc1 = __builtin_amdgcn_mfma_f32_16x16x32_f16(af, b1, acc1, 0, 0, 0);
                }
            }
            // -- recurrent part: h2[s-1], kgs 32 + kp*16 .. +16
            if (s > 0) {
                const f16* hp = p.h2all + (size_t)(s - 1) * (B_SZ * H_SZ);
                #pragma unroll
                for (int u = 0; u < 16; ++u) {
                    int kg = 32 + kp * 16 + u;
                    int kb = (kg - 32) * 32 + q * 8;
                    half8 b0 = ldB(kg, 0), b1 = ldB(kg, 1);
                    half8 af = *(const half8*)(hp + (size_t)(mt * 16 + n16) * H_SZ + kb);
                    acc0 = __builtin_amdgcn_mfma_f32_16x16x32_f16(af, b0, acc0, 0, 0, 0);
                    acc1 = __builtin_amdgcn_mfma_f32_16x16x32_f16(af, b1, acc1, 0, 0, 0);
                }
            }
        }

        // ---- merge the two k-halves: kp=1 writes, kp=0 adds (no tree) ----
        if (kp == 1) {
            wtile(mt * 2 + 0, acc0);
            wtile(mt * 2 + 1, acc1);
        }
        __syncthreads();
        if (kp == 0) {
            atile(mt * 2 + 0, acc0);
            atile(mt * 2 + 1, acc1);
            wtile(mt * 2 + 0, acc0);
            wtile(mt * 2 + 1, acc1);
        }
        __syncthreads();

        // ---- epilogue: all 512 threads, one (b, col) each ----
        {
            int b = tid >> 3, col = tid & 7;
            int bmt = b >> 4, r = b & 15;
            int base = (r >> 2) * 64 + (r & 3);   // lane-dump index of (row r, col 0)
            float iv = P[(bmt * 2 + 0) * 256 + base + col * 4]       + bl[col];
            float fv = P[(bmt * 2 + 0) * 256 + base + (col + 8) * 4] + bl[8 + col];
            float gv = P[(bmt * 2 + 1) * 256 + base + col * 4]       + bl[16 + col];
            float ov = P[(bmt * 2 + 1) * 256 + base + (col + 8) * 4] + bl[24 + col];
            float co = c_lds[tid];
            float ii = sigf(iv), ff = sigf(fv), gg = tanhfast(gv), oo = sigf(ov);
            float cn = ff * co + ii * gg;
            float hn = oo * tanhfast(cn);
            c_lds[tid] = cn;
            f16* dst = (layer ? p.h2all : p.h1all) + (size_t)s * (B_SZ * H_SZ);
            // write-through to coherent point (LLC): agent-scope atomic store
            unsigned short hb = __builtin_bit_cast(unsigned short, (f16)hn);
            __hip_atomic_store((unsigned short*)&dst[(size_t)b * H_SZ + jb + col], hb,
                               __ATOMIC_RELAXED, __HIP_MEMORY_SCOPE_AGENT);
        }
        __syncthreads();   // barrier drains vmcnt: all 8 waves' h stores at LLC
        if (tid == 0)
            __hip_atomic_store(myflag, s + 1, __ATOMIC_RELEASE, __HIP_MEMORY_SCOPE_AGENT);
    }
}

// ---------------------------------------------------------------------------
// Output projection: out[b,t] = h2[t,b,:] . w_out + b_out
// ---------------------------------------------------------------------------
__global__ __launch_bounds__(256) void gemv_kernel(
    const f16* __restrict__ h2all, const float* __restrict__ wout,
    const float* __restrict__ bout, float* __restrict__ out)
{
    int t = blockIdx.x;
    int wave = threadIdx.x >> 6, lane = threadIdx.x & 63;
    float w[16];
    #pragma unroll
    for (int u = 0; u < 16; ++u) w[u] = wout[lane * 16 + u];
    float b0 = bout[0];
    for (int b = wave; b < B_SZ; b += 4) {
        const f16* hp = h2all + ((size_t)t * B_SZ + b) * H_SZ + lane * 16;
        float sum = 0.f;
        #pragma unroll
        for (int u = 0; u < 16; ++u) sum += (float)hp[u] * w[u];
        #pragma unroll
        for (int off = 32; off; off >>= 1) sum += __shfl_down(sum, off, 64);
        if (lane == 0) out[(size_t)b * T_SEQ + t] = sum + b0;
    }
}

// ---------------------------------------------------------------------------
extern "C" void kernel_launch(void* const* d_in, const int* in_sizes, int n_in,
                              void* d_out, int out_size, void* d_ws, size_t ws_size,
                              hipStream_t stream)
{
    const float* x    = (const float*)d_in[0];
    const float* wih0 = (const float*)d_in[1];
    const float* whh0 = (const float*)d_in[2];
    const float* bih0 = (const float*)d_in[3];
    const float* bhh0 = (const float*)d_in[4];
    const float* wih1 = (const float*)d_in[5];
    const float* whh1 = (const float*)d_in[6];
    const float* bih1 = (const float*)d_in[7];
    const float* bhh1 = (const float*)d_in[8];
    const float* wout = (const float*)d_in[9];
    const float* bout = (const float*)d_in[10];
    float* out = (float*)d_out;

    char* ws = (char*)d_ws;
    size_t off = 0;
    auto alloc = [&](size_t bytes) -> void* {
        void* pp = ws + off;
        off += (bytes + 255) & ~(size_t)255;
        return pp;
    };
    f16* h1all = (f16*)alloc((size_t)T_SEQ * B_SZ * H_SZ * 2);    // 67 MB
    f16* h2all = (f16*)alloc((size_t)T_SEQ * B_SZ * H_SZ * 2);    // 67 MB
    int* flags = (int*)alloc(2 * 128 * 4);                        // 1 KB, packed

    (void)hipMemsetAsync(flags, 0, 2 * 128 * 4, stream);  // restart flags each replay

    Params pa;
    pa.x = x;
    pa.wih0 = wih0; pa.whh0 = whh0; pa.bih0 = bih0; pa.bhh0 = bhh0;
    pa.wih1 = wih1; pa.whh1 = whh1; pa.bih1 = bih1; pa.bhh1 = bhh1;
    pa.h1all = h1all; pa.h2all = h2all;
    pa.flags0 = flags; pa.flags1 = flags + 128;

    (void)hipFuncSetAttribute((const void*)persist_kernel,
                              hipFuncAttributeMaxDynamicSharedMemorySize, SMEM_BYTES);

    // Cooperative launch guarantees co-residency; under graph capture fall back
    // to a plain launch (identical kernel; 138KB LDS forces 1 block/CU and
    // grid == CU count, so all 256 blocks are co-resident by construction).
    hipStreamCaptureStatus cap = hipStreamCaptureStatusNone;
    (void)hipStreamIsCapturing(stream, &cap);
    bool launched = false;
    if (cap == hipStreamCaptureStatusNone) {
        void* kargs[] = { (void*)&pa };
        if (hipLaunchCooperativeKernel((const void*)persist_kernel, dim3(NBLK), dim3(NTHR),
                                       kargs, SMEM_BYTES, stream) == hipSuccess)
            launched = true;
    }
    if (!launched)
        persist_kernel<<<NBLK, NTHR, SMEM_BYTES, stream>>>(pa);

    gemv_kernel<<<T_SEQ, 256, 0, stream>>>(h2all, wout, bout, out);
}

// Round 7
// 6148.093 us; speedup vs baseline: 1.1571x; 1.1571x over previous
//
#include <hip/hip_runtime.h>

// Problem dims (fixed by reference)
#define T_SEQ 512
#define B_SZ  64
#define IN_SZ 512
#define H_SZ  1024
#define NBLK  256   // 128 blocks layer0 + 128 blocks layer1, 1 block/CU (LDS-forced)
#define NTHR  512   // 8 waves = 4 m-tiles x 2 k-halves
#define CNT_STRIDE 32   // ints: one counter per 128B line, rotating per step

typedef _Float16 f16;
typedef _Float16 half8 __attribute__((ext_vector_type(8)));
typedef float    f32x4 __attribute__((ext_vector_type(4)));

// LDS layout: wfrag 128K | P tiles 8KB | c 2KB | bias 128B | hstage 1KB
#define SM_WFRAG 0
#define SM_PART  131072
#define SM_C     (131072 + 8192)
#define SM_BIAS  (131072 + 8192 + 2048)
#define SM_STAGE (131072 + 8192 + 2048 + 128)
#define SMEM_BYTES (131072 + 8192 + 2048 + 128 + 1024)

struct Params {
    const float *x;
    const float *wih0, *whh0, *bih0, *bhh0;
    const float *wih1, *whh1, *bih1, *bhh1;
    f16 *h1all;    // [T][B][H]  rotating addresses: consumers use plain cached loads
    f16 *h2all;    // [T][B][H]
    int *cnt0, *cnt1;   // [T] counters, one 128B line each (rotating per step)
};

__device__ __forceinline__ float sigf(float x)     { return 1.f / (1.f + __expf(-x)); }
__device__ __forceinline__ float tanhfast(float x) { return 2.f / (1.f + __expf(-2.f * x)) - 1.f; }

// ---------------------------------------------------------------------------
// Persistent 2-layer LSTM, fence-free coherence:
//  - h published via agent-scope write-through atomic 8B stores (LDS-packed);
//  - step completion = one relaxed fetch_add on a per-step rotating counter
//    line (prior __syncthreads drained all h stores to LLC -> relaxed safe);
//  - consumers poll ONE counter line (all lanes same address, 1 request),
//    then read h with plain cached loads (fresh addresses, never stale).
// ---------------------------------------------------------------------------
__global__ __launch_bounds__(NTHR, 2) void persist_kernel(Params p)
{
    extern __shared__ char smem[];
    f16*   wfrag = (f16*)(smem + SM_WFRAG);
    float* P     = (float*)(smem + SM_PART);   // 8 slots x 256 f32, lane-dump layout
    float* c_lds = (float*)(smem + SM_C);      // [64][8] cell state, persistent
    float* bl    = (float*)(smem + SM_BIAS);   // [4 gates][8 cols]
    f16*   hst   = (f16*)(smem + SM_STAGE);    // [64][8] h staging for packed publish

    const int tid = threadIdx.x;
    const int l   = tid & 63, wv = tid >> 6;
    const int n16 = l & 15,  q  = l >> 4;
    const int mt  = wv & 3,  kp = wv >> 2;     // m-tile, k-half
    const int layer = blockIdx.x >> 7;
    const int bid   = blockIdx.x & 127;
    const int jb    = bid * 8;

    // ---- one-time staging: weights fp32 -> f16 fragments in LDS ----
    // frag f = kg*2 + nt; nt=0 holds gates {i,f}, nt=1 holds {g,o} for cols jb..jb+7
    {
        const int gate0 = n16 >> 3, c8 = n16 & 7;
        const int nfrag = layer ? 128 : 96;   // (K/32)*2
        for (int f = wv; f < nfrag; f += 8) {
            int kstep = f >> 1, nt = f & 1;
            int wrow = (nt * 2 + gate0) * H_SZ + jb + c8;
            const float* src;
            if (layer == 0) {
                src = (kstep < 16) ? p.wih0 + (size_t)wrow * IN_SZ + kstep * 32 + q * 8
                                   : p.whh0 + (size_t)wrow * H_SZ + (kstep - 16) * 32 + q * 8;
            } else {
                src = (kstep < 32) ? p.wih1 + (size_t)wrow * H_SZ + kstep * 32 + q * 8
                                   : p.whh1 + (size_t)wrow * H_SZ + (kstep - 32) * 32 + q * 8;
            }
            half8 hv;
            #pragma unroll
            for (int u = 0; u < 8; ++u) hv[u] = (f16)src[u];
            *(half8*)(wfrag + f * 512 + l * 8) = hv;
        }
        if (tid < 32) {
            int gate = tid >> 3, col = tid & 7;
            int wrow = gate * H_SZ + jb + col;
            bl[tid] = layer ? (p.bih1[wrow] + p.bhh1[wrow])
                            : (p.bih0[wrow] + p.bhh0[wrow]);
        }
        c_lds[tid] = 0.f;   // 512 = 64x8 exactly
    }
    __syncthreads();

    auto ldB = [&](int kg, int nt) -> half8 {
        return *(const half8*)(wfrag + (kg * 2 + nt) * 512 + l * 8);
    };
    // lane-dump tile layout: conflict-free contiguous b128 per wave
    auto wtile = [&](int slot, const f32x4& v) {
        *(f32x4*)(P + slot * 256 + l * 4) = v;
    };
    auto atile = [&](int slot, f32x4& a) {
        a += *(const f32x4*)(P + slot * 256 + l * 4);
    };
    int* mycnt = layer ? p.cnt1 : p.cnt0;

    for (int s = 0; s < T_SEQ; ++s) {
        f32x4 acc0 = {}, acc1 = {};   // nt=0 (i,f), nt=1 (g,o) for this wave's m-tile

        if (layer == 0) {
            // -- x part pre-poll (no cross-block dependency): kgs kp*8 .. +8
            #pragma unroll
            for (int u = 0; u < 8; ++u) {
                int kg = kp * 8 + u;
                int kb = kg * 32 + q * 8;
                half8 b0 = ldB(kg, 0), b1 = ldB(kg, 1);
                const float* ap = p.x + ((size_t)(mt * 16 + n16) * T_SEQ + s) * IN_SZ + kb;
                f32x4 xa = *(const f32x4*)ap;
                f32x4 xb = *(const f32x4*)(ap + 4);
                half8 af;
                #pragma unroll
                for (int u2 = 0; u2 < 4; ++u2) { af[u2] = (f16)xa[u2]; af[4 + u2] = (f16)xb[u2]; }
                acc0 = __builtin_amdgcn_mfma_f32_16x16x32_f16(af, b0, acc0, 0, 0, 0);
                acc1 = __builtin_amdgcn_mfma_f32_16x16x32_f16(af, b1, acc1, 0, 0, 0);
            }
            if (s > 0) {
                // ---- wait: all L0 blocks finished s-1 (one counter line) ----
                if (wv == 0) {
                    const int* c = p.cnt0 + (size_t)(s - 1) * CNT_STRIDE;
                    while (__hip_atomic_load(c, __ATOMIC_RELAXED, __HIP_MEMORY_SCOPE_AGENT) < 128)
                        __builtin_amdgcn_s_sleep(1);
                }
                __syncthreads();
                // -- recurrent part: h1[s-1], kgs 16 + kp*16 .. +16
                const f16* hp = p.h1all + (size_t)(s - 1) * (B_SZ * H_SZ);
                #pragma unroll
                for (int u = 0; u < 16; ++u) {
                    int kg = 16 + kp * 16 + u;
                    int kb = (kg - 16) * 32 + q * 8;
                    half8 b0 = ldB(kg, 0), b1 = ldB(kg, 1);
                    half8 af = *(const half8*)(hp + (size_t)(mt * 16 + n16) * H_SZ + kb);
                    acc0 = __builtin_amdgcn_mfma_f32_16x16x32_f16(af, b0, acc0, 0, 0, 0);
                    acc1 = __builtin_amdgcn_mfma_f32_16x16x32_f16(af, b1, acc1, 0, 0, 0);
                }
            }
        } else {
            // ---- wait: h1[s] ready (cnt0[s]==128); own group done s-1 ----
            {
                if (wv == 0) {
                    const int* cA = p.cnt0 + (size_t)s * CNT_STRIDE;
                    const int* cB = p.cnt1 + (size_t)(s - 1) * CNT_STRIDE;
                    bool dA = false, dB = (s == 0);
                    while (true) {
                        if (!dA) dA = __hip_atomic_load(cA, __ATOMIC_RELAXED, __HIP_MEMORY_SCOPE_AGENT) >= 128;
                        if (!dB) dB = __hip_atomic_load(cB, __ATOMIC_RELAXED, __HIP_MEMORY_SCOPE_AGENT) >= 128;
                        if (dA && dB) break;
                        __builtin_amdgcn_s_sleep(1);
                    }
                }
                __syncthreads();
            }
            // -- input part: h1[s], kgs kp*16 .. +16
            {
                const f16* hp = p.h1all + (size_t)s * (B_SZ * H_SZ);
                #pragma unroll
                for (int u = 0; u < 16; ++u) {
                    int kg = kp * 16 + u;
                    int kb = kg * 32 + q * 8;
                    half8 b0 = ldB(kg, 0), b1 = ldB(kg, 1);
                    half8 af = *(const half8*)(hp + (size_t)(mt * 16 + n16) * H_SZ + kb);
                    acc0 = __builtin_amdgcn_mfma_f32_16x16x32_f16(af, b0, acc0, 0, 0, 0);
                    acc1 = __builtin_amdgcn_mfma_f32_16x16x32_f16(af, b1, acc1, 0, 0, 0);
                }
            }
            // -- recurrent part: h2[s-1], kgs 32 + kp*16 .. +16
            if (s > 0) {
                const f16* hp = p.h2all + (size_t)(s - 1) * (B_SZ * H_SZ);
                #pragma unroll
                for (int u = 0; u < 16; ++u) {
                    int kg = 32 + kp * 16 + u;
                    int kb = (kg - 32) * 32 + q * 8;
                    half8 b0 = ldB(kg, 0), b1 = ldB(kg, 1);
                    half8 af = *(const half8*)(hp + (size_t)(mt * 16 + n16) * H_SZ + kb);
                    acc0 = __builtin_amdgcn_mfma_f32_16x16x32_f16(af, b0, acc0, 0, 0, 0);
                    acc1 = __builtin_amdgcn_mfma_f32_16x16x32_f16(af, b1, acc1, 0, 0, 0);
                }
            }
        }

        // ---- merge the two k-halves: kp=1 writes, kp=0 adds ----
        if (kp == 1) {
            wtile(mt * 2 + 0, acc0);
            wtile(mt * 2 + 1, acc1);
        }
        __syncthreads();
        if (kp == 0) {
            atile(mt * 2 + 0, acc0);
            atile(mt * 2 + 1, acc1);
            wtile(mt * 2 + 0, acc0);
            wtile(mt * 2 + 1, acc1);
        }
        __syncthreads();

        // ---- epilogue: all 512 threads compute one (b, col), stage to LDS ----
        {
            int b = tid >> 3, col = tid & 7;
            int bmt = b >> 4, r = b & 15;
            int base = (r >> 2) * 64 + (r & 3);   // lane-dump index of (row r, col 0)
            float iv = P[(bmt * 2 + 0) * 256 + base + col * 4]       + bl[col];
            float fv = P[(bmt * 2 + 0) * 256 + base + (col + 8) * 4] + bl[8 + col];
            float gv = P[(bmt * 2 + 1) * 256 + base + col * 4]       + bl[16 + col];
            float ov = P[(bmt * 2 + 1) * 256 + base + (col + 8) * 4] + bl[24 + col];
            float co = c_lds[tid];
            float ii = sigf(iv), ff = sigf(fv), gg = tanhfast(gv), oo = sigf(ov);
            float cn = ff * co + ii * gg;
            float hn = oo * tanhfast(cn);
            c_lds[tid] = cn;
            hst[b * 8 + col] = (f16)hn;
        }
        __syncthreads();
        // ---- packed publish: 128 threads x 8B agent-scope atomic stores ----
        if (tid < 128) {
            int b = tid >> 1, half = tid & 1;
            unsigned long long v = *(const unsigned long long*)(hst + b * 8 + half * 4);
            f16* dst = (layer ? p.h2all : p.h1all) + (size_t)s * (B_SZ * H_SZ);
            __hip_atomic_store((unsigned long long*)(dst + (size_t)b * H_SZ + jb + half * 4), v,
                               __ATOMIC_RELAXED, __HIP_MEMORY_SCOPE_AGENT);
        }
        __syncthreads();   // waitcnt vmcnt(0): all h stores acked at LLC
        if (tid == 0)
            __hip_atomic_fetch_add(mycnt + (size_t)s * CNT_STRIDE, 1,
                                   __ATOMIC_RELAXED, __HIP_MEMORY_SCOPE_AGENT);
    }
}

// ---------------------------------------------------------------------------
// Output projection: out[b,t] = h2[t,b,:] . w_out + b_out
// ---------------------------------------------------------------------------
__global__ __launch_bounds__(256) void gemv_kernel(
    const f16* __restrict__ h2all, const float* __restrict__ wout,
    const float* __restrict__ bout, float* __restrict__ out)
{
    int t = blockIdx.x;
    int wave = threadIdx.x >> 6, lane = threadIdx.x & 63;
    float w[16];
    #pragma unroll
    for (int u = 0; u < 16; ++u) w[u] = wout[lane * 16 + u];
    float b0 = bout[0];
    for (int b = wave; b < B_SZ; b += 4) {
        const f16* hp = h2all + ((size_t)t * B_SZ + b) * H_SZ + lane * 16;
        float sum = 0.f;
        #pragma unroll
        for (int u = 0; u < 16; ++u) sum += (float)hp[u] * w[u];
        #pragma unroll
        for (int off = 32; off; off >>= 1) sum += __shfl_down(sum, off, 64);
        if (lane == 0) out[(size_t)b * T_SEQ + t] = sum + b0;
    }
}

// ---------------------------------------------------------------------------
extern "C" void kernel_launch(void* const* d_in, const int* in_sizes, int n_in,
                              void* d_out, int out_size, void* d_ws, size_t ws_size,
                              hipStream_t stream)
{
    const float* x    = (const float*)d_in[0];
    const float* wih0 = (const float*)d_in[1];
    const float* whh0 = (const float*)d_in[2];
    const float* bih0 = (const float*)d_in[3];
    const float* bhh0 = (const float*)d_in[4];
    const float* wih1 = (const float*)d_in[5];
    const float* whh1 = (const float*)d_in[6];
    const float* bih1 = (const float*)d_in[7];
    const float* bhh1 = (const float*)d_in[8];
    const float* wout = (const float*)d_in[9];
    const float* bout = (const float*)d_in[10];
    float* out = (float*)d_out;

    char* ws = (char*)d_ws;
    size_t off = 0;
    auto alloc = [&](size_t bytes) -> void* {
        void* pp = ws + off;
        off += (bytes + 255) & ~(size_t)255;
        return pp;
    };
    f16* h1all = (f16*)alloc((size_t)T_SEQ * B_SZ * H_SZ * 2);     // 67 MB
    f16* h2all = (f16*)alloc((size_t)T_SEQ * B_SZ * H_SZ * 2);     // 67 MB
    int* cnts  = (int*)alloc(2 * T_SEQ * CNT_STRIDE * 4);          // 128 KB

    (void)hipMemsetAsync(cnts, 0, 2 * T_SEQ * CNT_STRIDE * 4, stream);  // zero counters each replay

    Params pa;
    pa.x = x;
    pa.wih0 = wih0; pa.whh0 = whh0; pa.bih0 = bih0; pa.bhh0 = bhh0;
    pa.wih1 = wih1; pa.whh1 = whh1; pa.bih1 = bih1; pa.bhh1 = bhh1;
    pa.h1all = h1all; pa.h2all = h2all;
    pa.cnt0 = cnts; pa.cnt1 = cnts + T_SEQ * CNT_STRIDE;

    (void)hipFuncSetAttribute((const void*)persist_kernel,
                              hipFuncAttributeMaxDynamicSharedMemorySize, SMEM_BYTES);

    // Cooperative launch guarantees co-residency; under graph capture fall back
    // to a plain launch (identical kernel; ~139KB LDS forces 1 block/CU and
    // grid == CU count, so all 256 blocks are co-resident by construction).
    hipStreamCaptureStatus cap = hipStreamCaptureStatusNone;
    (void)hipStreamIsCapturing(stream, &cap);
    bool launched = false;
    if (cap == hipStreamCaptureStatusNone) {
        void* kargs[] = { (void*)&pa };
        if (hipLaunchCooperativeKernel((const void*)persist_kernel, dim3(NBLK), dim3(NTHR),
                                       kargs, SMEM_BYTES, stream) == hipSuccess)
            launched = true;
    }
    if (!launched)
        persist_kernel<<<NBLK, NTHR, SMEM_BYTES, stream>>>(pa);

    gemv_kernel<<<T_SEQ, 256, 0, stream>>>(h2all, wout, bout, out);
}